// Round 6
// baseline (363.583 us; speedup 1.0000x reference)
//
#include <hip/hip_runtime.h>

// forward_warp bilinear scatter-add, v7: full-occupancy CSR gather.
// im0: [B,C,H,W] fp32, flow: [B,H,W,2] fp32 (dx,dy), out: [B,C,H,W] fp32
// B=8, C=16, H=512, W=512
//
// v6 post-mortem: 95us, every pipe ~30% -> latency-bound at 3 blocks/CU; the
// s_img float4 scatter-reads (addr si*16B, locally-dense si) hit an 8-way
// bank-quad conflict (most of the 7M conflict cycles).
// v7: (1) RAD=3 -> 38x38 halo (fallback absorbs ~0.5% of pixels exactly);
//     (2) img staged as TRANSPOSED b32 planes s_imgT[2][1444] -> conflict-free
//         reads AND writes; (3) CB=2 -> LDS 36.7KB -> 4 blocks/CU = 32
//         waves/CU (occupancy cap); (4) keep u16-weight CSR, fused two-cursor
//         gather, register async-stage (T14), XCD chunk swizzle (T1).

#define BB 8
#define CC 16
#define HH 512
#define WW 512
#define TIL 32             // dest tile edge
#define RAD 3              // halo radius; main path requires f in [-RAD, RAD)
#define REG (TIL + 2*RAD)  // 38
#define NSRC (REG*REG)     // 1444
#define NTHR 512
#define NREC ((NSRC + NTHR - 1) / NTHR)  // 3 records per thread (last partial)
#define NENT (NSRC * 4)    // hard bound on CSR entries: 5776 (fits u16)
#define CB 2               // channels per group (transposed b32 LDS planes)
#define NGRP (CC / CB)     // 8
#define NPIX (TIL * TIL)   // 1024

__global__ __launch_bounds__(NTHR, 8) void fwarp_tile(
    const float* __restrict__ im0,
    const float* __restrict__ flow,
    float* __restrict__ out)
{
    __shared__ unsigned s_ent[NENT];        // 23.1 KB  entry: si<<16 | u16 w
    __shared__ unsigned s_cur[NPIX / 2];    // 2 KB     2 x u16 per word
    __shared__ float    s_imgT[CB * NSRC];  // 11.6 KB  2 transposed img planes
    __shared__ unsigned s_wtot[8];
    // total 36.7 KB -> 4 blocks/CU -> 32 waves/CU (full occupancy)

    const int tid = threadIdx.x;
    // XCD chunk swizzle: 2048 blocks = 8 XCDs x 256; XCD k owns batch b=k.
    const int bid  = blockIdx.x;
    const int tile = ((bid & 7) << 8) | (bid >> 3);
    const int tcx = tile & 15;
    const int tcy = (tile >> 4) & 15;
    const int b   = tile >> 8;
    const int w0  = tcx * TIL;
    const int h0  = tcy * TIL;

    const float2* flow2 = (const float2*)flow + ((size_t)b << 18);

    // ---- Phase A: decode each source ONCE into registers ----
    float4 rw[NREC];       // corner weights (nw, ne, sw, se)
    int    rp0[NREC];      // ly*TIL + lx (NW corner pixel index, may be <0)
    int    rk[NREC];       // corner validity mask
    int    rgi[NREC];      // global spatial index for staging (0 if OOB)

    for (int j = tid; j < NPIX / 2; j += NTHR) s_cur[j] = 0u;

#pragma unroll
    for (int r = 0; r < NREC; ++r) {
        rk[r] = 0; rp0[r] = 0; rgi[r] = 0;
        rw[r] = make_float4(0.f, 0.f, 0.f, 0.f);
        const int i = tid + r * NTHR;
        if (i < NSRC) {
            const int ry = i / REG;
            const int rx = i - ry * REG;
            const int sy = h0 - RAD + ry;
            const int sx = w0 - RAD + rx;
            const bool inimg = (sx >= 0) & (sx < WW) & (sy >= 0) & (sy < HH);
            rgi[r] = inimg ? ((sy << 9) + sx) : 0;

            float fxv = 0.0f, fyv = 0.0f;
            if (inimg) {
                const float2 f = flow2[(sy << 9) + sx];
                fxv = f.x; fyv = f.y;
            }
            const float x = (float)sx + fxv;
            const float y = (float)sy + fyv;
            const float x0f = floorf(x);
            const float y0f = floorf(y);
            const int x0 = (int)x0f;
            const int y0 = (int)y0f;

            const bool inrange = (fxv >= -(float)RAD) & (fxv < (float)RAD) &
                                 (fyv >= -(float)RAD) & (fyv < (float)RAD);
            const bool valid = inimg && inrange &&
                               (x0 >= 0) && (x0 <= WW - 2) && (y0 >= 0) && (y0 <= HH - 2);

            const float fx = x - x0f;
            const float fy = y - y0f;
            const int lx = x0 - w0;
            const int ly = y0 - h0;

            const bool okW = (lx >= 0)  & (lx < TIL);
            const bool okE = (lx >= -1) & (lx < TIL - 1);
            const bool okN = (ly >= 0)  & (ly < TIL);
            const bool okS = (ly >= -1) & (ly < TIL - 1);

            const float wnw = (1.0f - fx) * (1.0f - fy);
            const float wne = fx * (1.0f - fy);
            const float wsw = (1.0f - fx) * fy;
            const float wse = fx * fy;

            int m = 0;
            if (valid && okN && okW && (wnw != 0.0f)) m |= 1;
            if (valid && okN && okE && (wne != 0.0f)) m |= 2;
            if (valid && okS && okW && (wsw != 0.0f)) m |= 4;
            if (valid && okS && okE && (wse != 0.0f)) m |= 8;

            rk[r]  = m;
            rp0[r] = ly * TIL + lx;
            rw[r]  = make_float4(wnw, wne, wsw, wse);
        }
    }
    __syncthreads();

    // ---- Phase 1: count contributions per dest pixel (packed u16 halves) ----
#pragma unroll
    for (int r = 0; r < NREC; ++r) {
        const int m = rk[r];
        const int p0 = rp0[r];
        if (m & 1) { const int p = p0;           atomicAdd(&s_cur[p >> 1], 1u << ((p & 1) * 16)); }
        if (m & 2) { const int p = p0 + 1;       atomicAdd(&s_cur[p >> 1], 1u << ((p & 1) * 16)); }
        if (m & 4) { const int p = p0 + TIL;     atomicAdd(&s_cur[p >> 1], 1u << ((p & 1) * 16)); }
        if (m & 8) { const int p = p0 + TIL + 1; atomicAdd(&s_cur[p >> 1], 1u << ((p & 1) * 16)); }
    }
    __syncthreads();

    // ---- Phase 2: exclusive prefix scan over 1024 counts (1 word/thread) ----
    {
        const int lane = tid & 63;
        const int wv   = tid >> 6;             // 0..7
        const unsigned word = s_cur[tid];
        const unsigned clo = word & 0xFFFFu;
        const unsigned chi = word >> 16;
        const unsigned mysum = clo + chi;
        unsigned inc = mysum;
#pragma unroll
        for (int d = 1; d < 64; d <<= 1) {
            const unsigned u = __shfl_up(inc, d);
            if (lane >= d) inc += u;
        }
        if (lane == 63) s_wtot[wv] = inc;
        __syncthreads();
        unsigned wpre = 0;
#pragma unroll
        for (int w = 0; w < 7; ++w) if (wv > w) wpre += s_wtot[w];
        const unsigned olo = wpre + inc - mysum;
        const unsigned ohi = olo + clo;
        s_cur[tid] = olo | (ohi << 16);        // packed row starts / cursors
    }
    __syncthreads();

    // capture row starts for our gather pixels BEFORE cursors get bumped
    int rbeg[2], rend[2];
#pragma unroll
    for (int k = 0; k < 2; ++k) {
        const int p = tid + k * NTHR;
        rbeg[k] = (int)((s_cur[p >> 1] >> ((p & 1) * 16)) & 0xFFFFu);
    }
    __syncthreads();

    // ---- Phase 3: fill CSR entries (si<<16 | u16 fixed-point weight) ----
#pragma unroll
    for (int r = 0; r < NREC; ++r) {
        const int i = tid + r * NTHR;          // source spat (local index)
        const int m = rk[r];
        const int p0 = rp0[r];
        const float4 w4 = rw[r];
        if (m & 1) { const int p = p0;
            const unsigned old = atomicAdd(&s_cur[p >> 1], 1u << ((p & 1) * 16));
            const unsigned s = (old >> ((p & 1) * 16)) & 0xFFFFu;
            s_ent[s] = ((unsigned)i << 16) | (unsigned)(w4.x * 65535.0f + 0.5f); }
        if (m & 2) { const int p = p0 + 1;
            const unsigned old = atomicAdd(&s_cur[p >> 1], 1u << ((p & 1) * 16));
            const unsigned s = (old >> ((p & 1) * 16)) & 0xFFFFu;
            s_ent[s] = ((unsigned)i << 16) | (unsigned)(w4.y * 65535.0f + 0.5f); }
        if (m & 4) { const int p = p0 + TIL;
            const unsigned old = atomicAdd(&s_cur[p >> 1], 1u << ((p & 1) * 16));
            const unsigned s = (old >> ((p & 1) * 16)) & 0xFFFFu;
            s_ent[s] = ((unsigned)i << 16) | (unsigned)(w4.z * 65535.0f + 0.5f); }
        if (m & 8) { const int p = p0 + TIL + 1;
            const unsigned old = atomicAdd(&s_cur[p >> 1], 1u << ((p & 1) * 16));
            const unsigned s = (old >> ((p & 1) * 16)) & 0xFFFFu;
            s_ent[s] = ((unsigned)i << 16) | (unsigned)(w4.w * 65535.0f + 0.5f); }
    }
    __syncthreads();
#pragma unroll
    for (int k = 0; k < 2; ++k) {
        const int p = tid + k * NTHR;
        rend[k] = (int)((s_cur[p >> 1] >> ((p & 1) * 16)) & 0xFFFFu);
    }

    const float* imb = im0 + ((size_t)(b * CC) << 18);
    float* outb      = out + ((size_t)(b * CC) << 18);

    // ---- Phase 4: 8 channel-groups, register-staged pipeline ----
    float2 vimg[NREC];

    // preload group 0 into registers
    {
        const float* c0 = imb;
#pragma unroll
        for (int r = 0; r < NREC; ++r) {
            const int i = tid + r * NTHR;
            if (i < NSRC) {
                vimg[r].x = c0[rgi[r]];
                vimg[r].y = c0[((size_t)1 << 18) + rgi[r]];
            }
        }
    }

    for (int g = 0; g < NGRP; ++g) {
        __syncthreads();   // previous gather done -> s_imgT reusable
        // transposed plane writes: consecutive i -> conflict-free
#pragma unroll
        for (int r = 0; r < NREC; ++r) {
            const int i = tid + r * NTHR;
            if (i < NSRC) {
                s_imgT[i]        = vimg[r].x;
                s_imgT[NSRC + i] = vimg[r].y;
            }
        }
        __syncthreads();   // s_imgT ready

        // issue next group's loads now; they complete under this group's gather
        if (g + 1 < NGRP) {
            const float* c0 = imb + ((size_t)((g + 1) * CB) << 18);
#pragma unroll
            for (int r = 0; r < NREC; ++r) {
                const int i = tid + r * NTHR;
                if (i < NSRC) {
                    vimg[r].x = c0[rgi[r]];
                    vimg[r].y = c0[((size_t)1 << 18) + rgi[r]];
                }
            }
        }

        // fused two-cursor gather: both pixels advance per round
        int j0 = rbeg[0], j1 = rbeg[1];
        const int e0 = rend[0], e1 = rend[1];
        float2 a0 = make_float2(0.f, 0.f);
        float2 a1 = make_float2(0.f, 0.f);
        while ((j0 < e0) | (j1 < e1)) {
            if (j0 < e0) {
                const unsigned e = s_ent[j0++];
                const float w  = (float)(e & 0xFFFFu) * (1.0f / 65535.0f);
                const int  si  = (int)(e >> 16);
                a0.x = fmaf(w, s_imgT[si],        a0.x);
                a0.y = fmaf(w, s_imgT[NSRC + si], a0.y);
            }
            if (j1 < e1) {
                const unsigned e = s_ent[j1++];
                const float w  = (float)(e & 0xFFFFu) * (1.0f / 65535.0f);
                const int  si  = (int)(e >> 16);
                a1.x = fmaf(w, s_imgT[si],        a1.x);
                a1.y = fmaf(w, s_imgT[NSRC + si], a1.y);
            }
        }

        // coalesced per-plane stores
        {
            const int p  = tid;
            const int dy = p >> 5;
            const int dx = p & 31;
            float* op = outb + ((size_t)(g * CB) << 18) + ((h0 + dy) << 9) + (w0 + dx);
            op[0]               = a0.x;
            op[(size_t)1 << 18] = a0.y;
        }
        {
            const int p  = tid + NTHR;
            const int dy = p >> 5;
            const int dx = p & 31;
            float* op = outb + ((size_t)(g * CB) << 18) + ((h0 + dy) << 9) + (w0 + dx);
            op[0]               = a1.x;
            op[(size_t)1 << 18] = a1.y;
        }
    }
}

// Exact fallback for sources with flow outside [-RAD, RAD): global atomic
// scatter, stream-ordered AFTER fwarp_tile's non-atomic stores.
__global__ __launch_bounds__(256) void fwarp_fallback(
    const float* __restrict__ im0,
    const float* __restrict__ flow,
    float* __restrict__ out)
{
    const int t = blockIdx.x * blockDim.x + threadIdx.x;   // handles 4 pixels
    const int idx0 = t << 2;

    const float4 fA = ((const float4*)flow)[(t << 1)];
    const float4 fB = ((const float4*)flow)[(t << 1) + 1];
    const float pfx[4] = {fA.x, fA.z, fB.x, fB.z};
    const float pfy[4] = {fA.y, fA.w, fB.y, fB.w};

#pragma unroll
    for (int k = 0; k < 4; ++k) {
        const float fxv = pfx[k];
        const float fyv = pfy[k];
        const bool inrange = (fxv >= -(float)RAD) & (fxv < (float)RAD) &
                             (fyv >= -(float)RAD) & (fyv < (float)RAD);
        if (inrange) continue;  // handled by fwarp_tile

        const int idx = idx0 + k;
        const int w = idx & (WW - 1);
        const int h = (idx >> 9) & (HH - 1);
        const int b = idx >> 18;

        const float x = (float)w + fxv;
        const float y = (float)h + fyv;
        const float x0f = floorf(x);
        const float y0f = floorf(y);
        const int x0 = (int)x0f;
        const int y0 = (int)y0f;
        if (x0 < 0 || x0 > WW - 2 || y0 < 0 || y0 > HH - 2) continue;

        const float fx = x - x0f;
        const float fy = y - y0f;
        const float wnw = (1.0f - fx) * (1.0f - fy);
        const float wne = fx * (1.0f - fy);
        const float wsw = (1.0f - fx) * fy;
        const float wse = fx * fy;

        const size_t plane = (size_t)HH * WW;
        const float* srcb = im0 + (size_t)b * CC * plane + (size_t)h * WW + w;
        float* dstb       = out + (size_t)b * CC * plane;
        const int o = y0 * WW + x0;

#pragma unroll
        for (int c = 0; c < CC; ++c) {
            const float v = srcb[c * plane];
            float* dc = dstb + c * plane;
            atomicAdd(dc + o,          v * wnw);
            atomicAdd(dc + o + 1,      v * wne);
            atomicAdd(dc + o + WW,     v * wsw);
            atomicAdd(dc + o + WW + 1, v * wse);
        }
    }
}

extern "C" void kernel_launch(void* const* d_in, const int* in_sizes, int n_in,
                              void* d_out, int out_size, void* d_ws, size_t ws_size,
                              hipStream_t stream) {
    const float* im0  = (const float*)d_in[0];
    const float* flow = (const float*)d_in[1];
    float* out = (float*)d_out;

    // Main kernel writes every output element exactly once -> no memset needed.
    const int n_tiles = BB * (HH / TIL) * (WW / TIL);  // 2048
    fwarp_tile<<<n_tiles, NTHR, 0, stream>>>(im0, flow, out);

    // Longer-range sources (|f| >= 3, ~0.5% of pixels): exact global-atomic
    // scatter, ordered after.
    const int n_pix = BB * HH * WW;                    // 2M; 4 px/thread
    fwarp_fallback<<<n_pix / (256 * 4), 256, 0, stream>>>(im0, flow, out);
}